// Round 1
// baseline (57.637 us; speedup 1.0000x reference)
//
#include <hip/hip_runtime.h>
#include <hip/hip_bf16.h>

#define NB 4
#define NH 16
#define SEQ 2048
#define EMB 512
#define DH 32
#define CHUNKQ 64
#define WIN 256

typedef __attribute__((ext_vector_type(8))) short short8;
typedef __attribute__((ext_vector_type(4))) float f32x4;

__device__ __forceinline__ ushort f2bf(float f) {
    union { float f; unsigned u; } c; c.f = f;
    unsigned u = c.u;
    unsigned r = u + 0x7FFFu + ((u >> 16) & 1u);   // round-to-nearest-even
    return (ushort)(r >> 16);
}

// LDS layout (bytes):
//   [0,      20992)  Vt  [32][328] bf16   (V transposed: Vt[dim][key])
//   [20992,  26112)  Qs  [64][40]  bf16   -- phase 1 only
//   [26112,  51712)  Ks  [320][40] bf16   -- phase 1 only
//   [20992,  62976)  Ps  [64][328] bf16   -- phase 2, overlays Qs+Ks
// total 62976 <= 64KB/block; 2 blocks/CU fit in 160KB LDS.

__global__ __launch_bounds__(256, 2)
void attn_chunk_kernel(const float* __restrict__ q, const float* __restrict__ k,
                       const float* __restrict__ v, float* __restrict__ out)
{
    constexpr int QK_PAD = 40;    // bf16 elems per Q/K row (32 + 8 pad)
    constexpr int KV_PAD = 328;   // bf16 elems per Vt/P row (320 + 8 pad)
    __shared__ __align__(16) unsigned char smem[62976];
    ushort* Vt = (ushort*)smem;
    ushort* Qs = (ushort*)(smem + 20992);
    ushort* Ks = (ushort*)(smem + 26112);
    ushort* Ps = (ushort*)(smem + 20992);

    const int cid = blockIdx.x & 31;          // chunk id
    const int h   = (blockIdx.x >> 5) & 15;   // head
    const int b   = blockIdx.x >> 9;          // batch
    const int q0  = cid * CHUNKQ;
    const int hi  = q0 + CHUNKQ;              // key range end (exclusive)
    const int kstart = (hi - 320 > 0) ? (hi - 320) : 0;
    const int KT  = hi - kstart;              // #keys staged; multiple of 32, <=320

    const int tid = threadIdx.x;

    // ---------------- stage Q, K, V (fp32 global -> bf16 LDS) ----------------
    {
        const int e4 = (tid & 7) * 4;   // dim offset 0..28
        const int r0 = tid >> 3;        // row 0..31
        #pragma unroll
        for (int it = 0; it < 2; ++it) {
            const int r = r0 + it * 32;
            const float4 f = *(const float4*)(q + ((size_t)(b * SEQ + q0 + r) * EMB + h * DH + e4));
            ushort* dst = Qs + r * QK_PAD + e4;
            dst[0] = f2bf(f.x); dst[1] = f2bf(f.y); dst[2] = f2bf(f.z); dst[3] = f2bf(f.w);
        }
        for (int r = r0; r < KT; r += 32) {
            const int kk = kstart + r;
            const size_t base = (size_t)(b * SEQ + kk) * EMB + h * DH + e4;
            const float4 fk = *(const float4*)(k + base);
            ushort* dk = Ks + r * QK_PAD + e4;
            dk[0] = f2bf(fk.x); dk[1] = f2bf(fk.y); dk[2] = f2bf(fk.z); dk[3] = f2bf(fk.w);
            const float4 fv = *(const float4*)(v + base);
            Vt[(e4 + 0) * KV_PAD + r] = f2bf(fv.x);
            Vt[(e4 + 1) * KV_PAD + r] = f2bf(fv.y);
            Vt[(e4 + 2) * KV_PAD + r] = f2bf(fv.z);
            Vt[(e4 + 3) * KV_PAD + r] = f2bf(fv.w);
        }
    }
    __syncthreads();

    // ---------------- QK^T ----------------
    const int w   = tid >> 6;    // wave 0..3: owns query rows [16w, 16w+16)
    const int l   = tid & 63;
    const int l16 = l & 15;
    const int kg  = l >> 4;      // 0..3
    const int k0  = kg * 8;

    // A-frag: lane holds Q[row=l16][k = kg*8 + j], contiguous 8 bf16
    const short8 aq = *(const short8*)(Qs + (16 * w + l16) * QK_PAD + k0);

    const f32x4 zero = {0.f, 0.f, 0.f, 0.f};
    f32x4 s4[20];
    #pragma unroll
    for (int t = 0; t < 20; ++t) {
        if (t * 16 < KT) {
            const short8 bk = *(const short8*)(Ks + (t * 16 + l16) * QK_PAD + k0);
            s4[t] = __builtin_amdgcn_mfma_f32_16x16x32_bf16(aq, bk, zero, 0, 0, 0);
        }
    }

    // ---------------- softmax (rows in registers; D-layout row = 4*kg + r) ----------------
    const float scale = 0.17677669529663687f;  // 1/sqrt(32)
    float mrow[4] = {-1e30f, -1e30f, -1e30f, -1e30f};
    #pragma unroll
    for (int t = 0; t < 20; ++t) {
        if (t * 16 < KT) {
            const int kk = kstart + t * 16 + l16;
            #pragma unroll
            for (int r = 0; r < 4; ++r) {
                const int i = q0 + 16 * w + 4 * kg + r;
                float s = s4[t][r] * scale;
                s = (kk >= i - (WIN - 1)) ? s : -1e30f;   // contiguous mask [i-255, hi)
                s4[t][r] = s;
                mrow[r] = fmaxf(mrow[r], s);
            }
        }
    }
    #pragma unroll
    for (int r = 0; r < 4; ++r) {
        #pragma unroll
        for (int m = 1; m <= 8; m <<= 1) mrow[r] = fmaxf(mrow[r], __shfl_xor(mrow[r], m));
    }
    float srow[4] = {0.f, 0.f, 0.f, 0.f};
    #pragma unroll
    for (int t = 0; t < 20; ++t) {
        if (t * 16 < KT) {
            #pragma unroll
            for (int r = 0; r < 4; ++r) {
                const float p = __expf(s4[t][r] - mrow[r]);
                s4[t][r] = p;
                srow[r] += p;
            }
        }
    }
    #pragma unroll
    for (int r = 0; r < 4; ++r) {
        #pragma unroll
        for (int m = 1; m <= 8; m <<= 1) srow[r] += __shfl_xor(srow[r], m);
    }

    __syncthreads();   // all waves done reading Qs/Ks before Ps overlays them

    // ---------------- P (D-layout regs) -> LDS bf16, A-frag layout for PV ----------------
    #pragma unroll
    for (int t = 0; t < 20; ++t) {
        if (t * 16 < KT) {
            ushort* dst = Ps + (16 * w + 4 * kg) * KV_PAD + (t * 16 + l16);
            dst[0 * KV_PAD] = f2bf(s4[t][0]);
            dst[1 * KV_PAD] = f2bf(s4[t][1]);
            dst[2 * KV_PAD] = f2bf(s4[t][2]);
            dst[3 * KV_PAD] = f2bf(s4[t][3]);
        }
    }
    __syncthreads();   // (P rows are wave-private; barrier for safety/order)

    // ---------------- PV ----------------
    f32x4 o0 = zero, o1 = zero;
    #pragma unroll
    for (int t2 = 0; t2 < 10; ++t2) {
        if (t2 * 32 < KT) {
            const short8 pa  = *(const short8*)(Ps + (16 * w + l16) * KV_PAD + t2 * 32 + k0);
            const short8 bv0 = *(const short8*)(Vt + l16 * KV_PAD + t2 * 32 + k0);
            const short8 bv1 = *(const short8*)(Vt + (16 + l16) * KV_PAD + t2 * 32 + k0);
            o0 = __builtin_amdgcn_mfma_f32_16x16x32_bf16(pa, bv0, o0, 0, 0, 0);
            o1 = __builtin_amdgcn_mfma_f32_16x16x32_bf16(pa, bv1, o1, 0, 0, 0);
        }
    }

    // ---------------- epilogue: normalize by row sum, write fp32 ----------------
    #pragma unroll
    for (int r = 0; r < 4; ++r) {
        const int i = q0 + 16 * w + 4 * kg + r;
        const float inv = 1.0f / srow[r];
        float* dst = out + (size_t)(b * SEQ + i) * EMB + h * DH;
        dst[l16]      = o0[r] * inv;
        dst[16 + l16] = o1[r] * inv;
    }
}

extern "C" void kernel_launch(void* const* d_in, const int* in_sizes, int n_in,
                              void* d_out, int out_size, void* d_ws, size_t ws_size,
                              hipStream_t stream) {
    const float* q = (const float*)d_in[0];
    const float* k = (const float*)d_in[1];
    const float* v = (const float*)d_in[2];
    float* out = (float*)d_out;
    const int grid = NB * NH * (SEQ / CHUNKQ);   // 4*16*32 = 2048 blocks
    attn_chunk_kernel<<<grid, 256, 0, stream>>>(q, k, v, out);
}